// Round 8
// baseline (44.854 us; speedup 1.0000x reference)
//
#include <hip/hip_runtime.h>
#include <math.h>

// YOLOv3 detection-head decode.
// prediction: [B=32, 255, 52, 52] f32 ; anchors: [3,2] f32
// out: [B, 52*52*3, 85] f32 ; per (b,gj) slice output is 13,260 contiguous
// floats, e = gi*255 + c (c = a*85+attr).
//
// Block = (slice, gi-chunk), chunks {16,16,16,4} gi (all mult-of-4 => both
// sides float4-exact & 16B-aligned; all index math is shifts).
//   Load  : row-exclusive aligned float4 -> output-order flat LDS.
//   Bulk  : branch-free: ds_read_b128 -> 4x(mul,exp2,add,rcp) sigmoid ->
//           nontemporal dwordx4 store. NO attr decode, NO selects (251/255
//           columns are plain sigmoid).
//   Fixup : after __syncthreads (vmcnt drained => ordered), 12*NG threads
//           recompute x/y/w/h columns from LDS and overwrite 4B each.
// XCD swizzle: a slice's 4 chunks stay on one XCD (L2-shared row edges).

#define BB 32
#define GG 52
#define NROWS 255
#define PLANE (GG * GG)        // 2704
#define SLICE_N (GG * NROWS)   // 13260
#define L2E 1.442695040889f

typedef float f32x4 __attribute__((ext_vector_type(4)));

__device__ __forceinline__ float fast_sigmoid(float x) {
    return __builtin_amdgcn_rcpf(1.0f + __builtin_amdgcn_exp2f(-L2E * x));
}

template<int GI0, int NG>
__device__ __forceinline__ void decode_body(int slice, int t,
                                            const float* __restrict__ in,
                                            const float* __restrict__ anchors,
                                            float* __restrict__ out,
                                            float* __restrict__ tile) {
    const int b  = slice / GG;
    const int gj = slice - b * GG;

    constexpr int NQROW = NG / 4;            // 4 or 1
    constexpr int TOTQ  = NROWS * NQROW;     // 1020 or 255
    constexpr int NIT   = (TOTQ + 255) / 256;

    const float* __restrict__ src =
        in + (size_t)b * NROWS * PLANE + gj * GG + GI0;

    // ---- load: row-exclusive aligned float4, scatter to output order ----
    #pragma unroll
    for (int it = 0; it < NIT; ++it) {
        const int idx = t + it * 256;
        if ((TOTQ % 256 == 0) || it < NIT - 1 || idx < TOTQ) {
            int row, q;
            if constexpr (NQROW == 4) { row = idx >> 2; q = idx & 3; }
            else                      { row = idx;      q = 0;       }
            const f32x4 v =
                *reinterpret_cast<const f32x4*>(src + (size_t)row * PLANE + 4 * q);
            const int e = (4 * q) * NROWS + row;   // gi_local = 4q+k, c = row
            tile[e            ] = v.x;
            tile[e +     NROWS] = v.y;
            tile[e + 2 * NROWS] = v.z;
            tile[e + 3 * NROWS] = v.w;
        }
    }

    __syncthreads();

    // ---- bulk: branch-free sigmoid stream (251/255 columns correct) ----
    float* __restrict__ dst = out + (size_t)slice * SLICE_N + GI0 * NROWS;

    #pragma unroll
    for (int it = 0; it < NIT; ++it) {
        const int i = t + it * 256;
        if ((TOTQ % 256 == 0) || it < NIT - 1 || i < TOTQ) {
            const f32x4 u = *reinterpret_cast<const f32x4*>(&tile[4 * i]);
            f32x4 o;
            o.x = fast_sigmoid(u.x);
            o.y = fast_sigmoid(u.y);
            o.z = fast_sigmoid(u.z);
            o.w = fast_sigmoid(u.w);
            __builtin_nontemporal_store(o, reinterpret_cast<f32x4*>(dst + 4 * i));
        }
    }

    // order bulk NT-stores before fixup overwrites (barrier drains vmcnt)
    __syncthreads();

    // ---- fixup: x/y/w/h columns (12 of 255), 4B overwrites ----
    const int gi_l = t >> 4;          // 0..15
    const int j    = t & 15;          // 0..15; active if j < 12
    if (j < 12 && gi_l < NG) {
        const int a    = j >> 2;
        const int attr = j & 3;
        const int c    = a * 85 + attr;
        const int e    = gi_l * NROWS + c;
        const float x  = tile[e];
        float r;
        if (attr == 0)      r = (fast_sigmoid(x) + (float)(GI0 + gi_l)) * 8.0f;
        else if (attr == 1) r = (fast_sigmoid(x) + (float)gj) * 8.0f;
        else {
            // w/h: exp(x) * anchor_px  ((anchor/stride)*stride = anchor)
            const float anc = anchors[a * 2 + (attr & 1)];
            r = __builtin_amdgcn_exp2f(L2E * x) * anc;
        }
        dst[e] = r;
    }
}

__global__ __launch_bounds__(256, 8)
void detect_decode_kernel(const float* __restrict__ in,
                          const float* __restrict__ anchors,
                          float* __restrict__ out) {
    __shared__ float tile[16 * NROWS];   // 16,320 B (max chunk)

    // XCD-bijective swizzle: grid = 6656 = 8*832; a slice's 4 chunks occupy
    // consecutive slots on the SAME xcd.
    const int B     = blockIdx.x;
    const int xcd   = B & 7;
    const int slot  = B >> 3;            // 0..831
    const int chunk = slot & 3;
    const int slice = ((slot >> 2) << 3) | xcd;   // 0..1663
    const int t     = threadIdx.x;

    if      (chunk == 0) decode_body< 0, 16>(slice, t, in, anchors, out, tile);
    else if (chunk == 1) decode_body<16, 16>(slice, t, in, anchors, out, tile);
    else if (chunk == 2) decode_body<32, 16>(slice, t, in, anchors, out, tile);
    else                 decode_body<48,  4>(slice, t, in, anchors, out, tile);
}

extern "C" void kernel_launch(void* const* d_in, const int* in_sizes, int n_in,
                              void* d_out, int out_size, void* d_ws, size_t ws_size,
                              hipStream_t stream) {
    const float* pred    = (const float*)d_in[0];
    const float* anchors = (const float*)d_in[1];
    float* out = (float*)d_out;

    const int nblocks = BB * GG * 4;   // 6656
    detect_decode_kernel<<<nblocks, 256, 0, stream>>>(pred, anchors, out);
}